// Round 1
// baseline (28.621 us; speedup 1.0000x reference)
//
#include <hip/hip_runtime.h>

// AnchorProcessor: x[8,255,128,128] f32 -> out[8,18,128,128] f32
// out[n, a*6+j, h, w]: j=0..3 boxes (per-n), j=4 smax, j=5 sarg (broadcast over n,
// reduced over n*80+c flat index with first-max argmax semantics).

#define NN   8
#define AA   3
#define CLSN 80
#define HW   16384           // 128*128
#define CH   255             // 3*85

__global__ __launch_bounds__(256)
void anchor_kernel(const float* __restrict__ x, float* __restrict__ out) {
    // tid = n*32 + p ; block covers 32 consecutive flat pixels
    const int tid = threadIdx.x;
    const int p   = tid & 31;
    const int n   = tid >> 5;
    const int pix = blockIdx.x * 32 + p;     // flat pixel index h*128+w
    const int h   = pix >> 7;
    const int w   = pix & 127;

    const float anchw[AA] = {116.f, 156.f, 373.f};
    const float anchh[AA] = { 90.f, 198.f, 326.f};

    // per-(n,pixel) base offset (fits in 32-bit: max ~33.4M)
    const int nbase = n * (CH * HW) + pix;

    __shared__ float s_val[AA][NN][32];
    __shared__ int   s_idx[AA][NN][32];

    #pragma unroll
    for (int a = 0; a < AA; ++a) {
        const int abase = nbase + (a * 85) * HW;
        const float tx  = x[abase + 0 * HW];
        const float ty  = x[abase + 1 * HW];
        const float tw  = x[abase + 2 * HW];
        const float th  = x[abase + 3 * HW];
        const float obj = x[abase + 4 * HW];

        const float bx = 1.0f / (1.0f + __expf(-tx)) + (float)w;
        const float by = 1.0f / (1.0f + __expf(-ty)) + (float)h;
        const float bw = tw * anchw[a];
        const float bh = th * anchh[a];

        const int obase = (n * 18 + a * 6) * HW + pix;
        out[obase + 0 * HW] = bx;
        out[obase + 1 * HW] = by;
        out[obase + 2 * HW] = bw;
        out[obase + 3 * HW] = bh;

        // class-score reduction for this n (flat idx = n*80 + c, first-max)
        float best = -__builtin_inff();
        int   bidx = n * CLSN;
        #pragma unroll 8
        for (int c = 0; c < CLSN; ++c) {
            const float v = x[abase + (5 + c) * HW] * obj;
            if (v > best) { best = v; bidx = n * CLSN + c; }
        }
        s_val[a][n][p] = best;
        s_idx[a][n][p] = bidx;
    }
    __syncthreads();

    // combine the 8 per-n partials; every thread computes the final (broadcast)
    // and writes its own n's copy of smax/sarg.
    #pragma unroll
    for (int a = 0; a < AA; ++a) {
        float best = s_val[a][0][p];
        int   bidx = s_idx[a][0][p];
        #pragma unroll
        for (int nn = 1; nn < NN; ++nn) {
            const float v  = s_val[a][nn][p];
            const int   id = s_idx[a][nn][p];
            if (v > best || (v == best && id < bidx)) { best = v; bidx = id; }
        }
        const int obase = (n * 18 + a * 6) * HW + pix;
        out[obase + 4 * HW] = best;
        out[obase + 5 * HW] = (float)bidx;
    }
}

extern "C" void kernel_launch(void* const* d_in, const int* in_sizes, int n_in,
                              void* d_out, int out_size, void* d_ws, size_t ws_size,
                              hipStream_t stream) {
    const float* x = (const float*)d_in[0];
    float* out = (float*)d_out;
    // 16384 pixels / 32 per block = 512 blocks, 256 threads each
    dim3 grid(HW / 32);
    dim3 block(256);
    hipLaunchKernelGGL(anchor_kernel, grid, block, 0, stream, x, out);
}